// Round 9
// baseline (1209.799 us; speedup 1.0000x reference)
//
#include <hip/hip_runtime.h>
#include <hip/hip_bf16.h>

// UnrolledRNN on MI355X (gfx950) — two-phase; 16-wave dual-tile recurrence.
// Phase 1 (parallel, all CUs): xh[b,t,:] = x[b,t,:] @ Wxh + bxh -> bf16 in d_ws.
// Phase 2 (serial, 8 blocks x 16 waves = 1024 thr): h = tanh(xh_t + h @ Whh).
//   R8 (2 waves/SIMD, halved work) won: 1160->1025 cyc/step. R5 (dual tile,
//   doubled per-wave work) lost. Combine correctly: dual tile with CONSTANT
//   per-wave work -> 4 waves/SIMD, each SIMD interleaving two independent
//   batch-tile chains (A,B) x two u-halves. Per wave per step (same as R8):
//   8B xh load, 4 ds_read_b128, 4 independent MFMA + add tree, 4 tanh,
//   1 ds_write_b64. sigma mapping (R3-validated): wave (tile,jw,u) owns
//   j = 32jw + 8lg + 4u + r; packed tanh output IS the half B-frag.
//   2-zone parity + 1 barrier/step (shared by both tiles, symmetric).

#define SEQ   2048
#define HID   128
#define BATCH 256
#define BD    16

typedef __attribute__((ext_vector_type(8))) short    short8;
typedef __attribute__((ext_vector_type(4))) float    f32x4;
typedef __attribute__((ext_vector_type(4))) float    f4;
typedef __attribute__((ext_vector_type(2))) unsigned u32x2;
typedef __attribute__((ext_vector_type(4))) unsigned u32x4;

union F8 { unsigned u[4]; short8 s; };

__device__ __forceinline__ unsigned pkbf(float a, float b) {
    union { __hip_bfloat16 h[2]; unsigned u; } t;
    t.h[0] = __float2bfloat16(a);
    t.h[1] = __float2bfloat16(b);
    return t.u;
}

__device__ __forceinline__ float blo(unsigned u) {
    union { unsigned v; float f; } t; t.v = u << 16; return t.f;
}
__device__ __forceinline__ float bhi(unsigned u) {
    union { unsigned v; float f; } t; t.v = u & 0xffff0000u; return t.f;
}

__device__ __forceinline__ float tanh_fast(float x) {
    float e = __builtin_amdgcn_exp2f(x * 2.8853900817779268f);
    return 1.0f - 2.0f * __builtin_amdgcn_rcpf(e + 1.0f);
}

__device__ __forceinline__ void block_sync() {
    asm volatile("s_waitcnt lgkmcnt(0)" ::: "memory");
    __builtin_amdgcn_s_barrier();
    asm volatile("" ::: "memory");
}

#define MFMA16(A,B,C) __builtin_amdgcn_mfma_f32_16x16x32_bf16((A),(B),(C),0,0,0)

// =====================================================================
// Phase 1: xh = x @ Wxh + bxh, bf16 [BATCH*SEQ][HID] in ws (plain j order).
// =====================================================================
__launch_bounds__(256, 1)
__global__ void xh_gemm_kernel(const float* __restrict__ x,
                               const float* __restrict__ Wxh,
                               const float* __restrict__ bxh,
                               __hip_bfloat16* __restrict__ xh)
{
    const int tid  = threadIdx.x;
    const int wv   = tid >> 6;
    const int lane = tid & 63;
    const int lg   = lane >> 4;
    const int lm   = lane & 15;

    const int gw = blockIdx.x * 4 + wv;
    const int NW = gridDim.x * 4;
    const int NT = (BATCH * SEQ) / 16;

    short8 wa[8][4];
    {
        #pragma unroll
        for (int T = 0; T < 8; ++T) {
            #pragma unroll
            for (int c = 0; c < 4; ++c) {
                F8 f;
                #pragma unroll
                for (int e2 = 0; e2 < 4; ++e2) {
                    int k = 32*c + 8*lg + 2*e2;
                    f.u[e2] = pkbf(Wxh[(size_t)k*HID + 16*T + lm],
                                   Wxh[(size_t)(k+1)*HID + 16*T + lm]);
                }
                wa[T][c] = f.s;
            }
        }
    }
    float bb[8][4];
    #pragma unroll
    for (int T = 0; T < 8; ++T)
        #pragma unroll
        for (int r = 0; r < 4; ++r)
            bb[T][r] = bxh[16*T + 4*lg + r];

    for (int tile = gw; tile < NT; tile += NW) {
        const float* xp = x + (size_t)tile*16*HID + (size_t)lm*HID + 8*lg;
        f4 s[8];
        #pragma unroll
        for (int c = 0; c < 4; ++c) {
            s[2*c]   = *(const f4*)(xp + 32*c);
            s[2*c+1] = *(const f4*)(xp + 32*c + 4);
        }
        F8 xf[4];
        #pragma unroll
        for (int c = 0; c < 4; ++c) {
            xf[c].u[0] = pkbf(s[2*c][0],   s[2*c][1]);
            xf[c].u[1] = pkbf(s[2*c][2],   s[2*c][3]);
            xf[c].u[2] = pkbf(s[2*c+1][0], s[2*c+1][1]);
            xf[c].u[3] = pkbf(s[2*c+1][2], s[2*c+1][3]);
        }
        __hip_bfloat16* op = xh + (size_t)(tile*16 + lm) * HID;
        #pragma unroll
        for (int T = 0; T < 8; ++T) {
            f32x4 acc = {bb[T][0], bb[T][1], bb[T][2], bb[T][3]};
            #pragma unroll
            for (int c = 0; c < 4; ++c)
                acc = MFMA16(wa[T][c], xf[c].s, acc);
            u32x2 w;
            w[0] = pkbf(acc[0], acc[1]);
            w[1] = pkbf(acc[2], acc[3]);
            *reinterpret_cast<u32x2*>(op + 16*T + 4*lg) = w;
        }
    }
}

// =====================================================================
// Phase 2: 16-wave dual-tile recurrence.
// LDS per tile ti: zone[P][c][lane][16B] at ti*8192 + P*4096 + c*1024 + lane*16.
// Wave (ti,jw,u) writes half-frag (8B) at zone^1 + jw*1024 + lane*16 + 8u.
// =====================================================================

#define REC16W_STEP(S, P, POFF, TRT)                                          \
    {                                                                          \
        f32x4 a;                                                               \
        a[0] = blo(S[0]); a[1] = bhi(S[0]);                                    \
        a[2] = blo(S[1]); a[3] = bhi(S[1]);                                    \
        if ((TRT) + 4 < SEQ) S = *(const u32x2*)(xq + (POFF)*256);             \
        block_sync(); /* h_t frags complete in zone[P] of both tiles */        \
        const char* rb = zbase + (P)*4096;                                     \
        short8 f0 = *(const short8*)(rb + 0*1024 + lane*16);                   \
        short8 f1 = *(const short8*)(rb + 1*1024 + lane*16);                   \
        short8 f2 = *(const short8*)(rb + 2*1024 + lane*16);                   \
        short8 f3 = *(const short8*)(rb + 3*1024 + lane*16);                   \
        f32x4 t1 = {0.f,0.f,0.f,0.f};                                          \
        f32x4 t2 = {0.f,0.f,0.f,0.f};                                          \
        f32x4 t3 = {0.f,0.f,0.f,0.f};                                          \
        a  = MFMA16(whf[0], f0, a);                                            \
        t1 = MFMA16(whf[1], f1, t1);                                           \
        t2 = MFMA16(whf[2], f2, t2);                                           \
        t3 = MFMA16(whf[3], f3, t3);                                           \
        a += (t1 + t2) + t3;                                                   \
        u32x2 nf;                                                              \
        nf[0] = pkbf(tanh_fast(a[0]), tanh_fast(a[1]));                        \
        nf[1] = pkbf(tanh_fast(a[2]), tanh_fast(a[3]));                        \
        *reinterpret_cast<u32x2*>(zbase + ((P)^1)*4096 + wr) = nf;             \
    }

__launch_bounds__(1024, 1)
__global__ void rnn_rec16w_kernel(const __hip_bfloat16* __restrict__ xh,
                                  const float* __restrict__ h0,
                                  const float* __restrict__ Whh,
                                  const float* __restrict__ Wout,
                                  const float* __restrict__ bout,
                                  float* __restrict__ out)
{
    __shared__ __align__(16) char lds[2 * 8192];  // 2 tiles x 2 zones x 4KB

    const int tid  = threadIdx.x;
    const int wv   = tid >> 6;         // 0..15
    const int ti   = wv >> 3;          // tile 0/1
    const int jw   = wv & 3;           // j-slice
    const int u    = (wv >> 2) & 1;    // half within slice
    const int lane = tid & 63;
    const int lg   = lane >> 4;
    const int lm   = lane & 15;
    const int b0   = blockIdx.x * 32;  // 32 batch rows per block

    char* zbase = lds + ti * 8192;

    // Whh A-frags (R3-validated sigma, u fixed per wave):
    // whf[c] lane (lg,lm) elem-pair e2 = Whh[32c+8lg+2e2 (+1)][scol],
    // scol = 32jw + 8*(lm>>2) + 4u + (lm&3). Identical for both tiles.
    short8 whf[4];
    {
        const int scol = 32*jw + 8*(lm >> 2) + 4*u + (lm & 3);
        #pragma unroll
        for (int c = 0; c < 4; ++c) {
            F8 f;
            #pragma unroll
            for (int e2 = 0; e2 < 4; ++e2) {
                int k = 32*c + 8*lg + 2*e2;
                f.u[e2] = pkbf(Whh[(size_t)k*HID + scol],
                               Whh[(size_t)(k+1)*HID + scol]);
            }
            whf[c] = f.s;
        }
    }

    // LDS write offset for this wave's half-frag (zone-relative)
    const int wr = jw*1024 + lane*16 + 8*u;

    // init zone0 from h0: this wave's 4 values = h0[row][32jw+8lg+4u+{0..3}]
    {
        const float* hp = h0 + (size_t)(b0 + 16*ti + lm) * HID + 32*jw + 8*lg + 4*u;
        f4 v = *(const f4*)(hp);
        u32x2 iv;
        iv[0] = pkbf(v[0], v[1]);
        iv[1] = pkbf(v[2], v[3]);
        *reinterpret_cast<u32x2*>(zbase + wr) = iv;
    }

    // xh stream: 8B/lane/step at xh[row][t][32jw+8lg+4u], 4-deep prefetch
    const char* xq = (const char*)xh + (size_t)(b0 + 16*ti + lm) * SEQ * 256
                   + (size_t)(32*jw + 8*lg + 4*u) * 2;

    u32x2 sA = *(const u32x2*)(xq + 0*256);
    u32x2 sB = *(const u32x2*)(xq + 1*256);
    u32x2 sC = *(const u32x2*)(xq + 2*256);
    u32x2 sD = *(const u32x2*)(xq + 3*256);

    for (int t = 0; t < SEQ; t += 4) {
        REC16W_STEP(sA, 0, 4, t);
        REC16W_STEP(sB, 1, 5, t + 1);
        REC16W_STEP(sC, 0, 6, t + 2);
        REC16W_STEP(sD, 1, 7, t + 3);
        xq += 4 * 256;
    }

    // epilogue: out = h_last @ Wout + bout; h_SEQ frags in zone0 of each tile.
    // Wave wv computes output tile T = wv&7 for its batch tile ti.
    block_sync();
    {
        const int T = wv & 7;
        short8 h0f = *reinterpret_cast<const short8*>(zbase + 0*1024 + lane*16);
        short8 h1f = *reinterpret_cast<const short8*>(zbase + 1*1024 + lane*16);
        short8 h2f = *reinterpret_cast<const short8*>(zbase + 2*1024 + lane*16);
        short8 h3f = *reinterpret_cast<const short8*>(zbase + 3*1024 + lane*16);

        f32x4 o = {bout[16*T + 4*lg + 0], bout[16*T + 4*lg + 1],
                   bout[16*T + 4*lg + 2], bout[16*T + 4*lg + 3]};
        #pragma unroll
        for (int c = 0; c < 4; ++c) {
            F8 f;
            #pragma unroll
            for (int e2 = 0; e2 < 4; ++e2) {
                int k = 32*c + 8*lg + 2*e2;
                f.u[e2] = pkbf(Wout[(size_t)k*HID + 16*T + lm],
                               Wout[(size_t)(k+1)*HID + 16*T + lm]);
            }
            const short8 hf = (c == 0) ? h0f : (c == 1) ? h1f : (c == 2) ? h2f : h3f;
            o = MFMA16(f.s, hf, o);
        }
        float* op = out + (size_t)(b0 + 16*ti + lm) * HID + 16*T + 4*lg;
        *reinterpret_cast<f4*>(op) = o;
    }
}

// =====================================================================
// Fallback: verified round-1 monolithic kernel (used if ws too small).
// =====================================================================
#define RNN_STEP(SLOT, P, POFF, TRT)                                          \
    {                                                                          \
        F8 xf[4];                                                              \
        _Pragma("unroll")                                                      \
        for (int c = 0; c < 4; ++c) {                                          \
            xf[c].u[0] = pkbf(SLOT[2*c][0],   SLOT[2*c][1]);                   \
            xf[c].u[1] = pkbf(SLOT[2*c][2],   SLOT[2*c][3]);                   \
            xf[c].u[2] = pkbf(SLOT[2*c+1][0], SLOT[2*c+1][1]);                 \
            xf[c].u[3] = pkbf(SLOT[2*c+1][2], SLOT[2*c+1][3]);                 \
        }                                                                      \
        if ((TRT) + 2 < SEQ) {                                                 \
            _Pragma("unroll")                                                  \
            for (int c = 0; c < 4; ++c) {                                      \
                SLOT[2*c]   = *(const f4*)(xq + (POFF)*HID + 32*c);            \
                SLOT[2*c+1] = *(const f4*)(xq + (POFF)*HID + 32*c + 4);        \
            }                                                                  \
        }                                                                      \
        f32x4 a0 = {bx[0][0], bx[0][1], bx[0][2], bx[0][3]};                   \
        f32x4 a1 = {bx[1][0], bx[1][1], bx[1][2], bx[1][3]};                   \
        _Pragma("unroll")                                                      \
        for (int c = 0; c < 4; ++c) {                                          \
            a0 = MFMA16(wxh[0][c], xf[c].s, a0);                               \
            a1 = MFMA16(wxh[1][c], xf[c].s, a1);                               \
        }                                                                      \
        block_sync();                                                          \
        _Pragma("unroll")                                                      \
        for (int c = 0; c < 4; ++c) {                                          \
            short8 hf = *reinterpret_cast<const short8*>(lds + (P)*4096 + rd[c]); \
            a0 = MFMA16(whh[0][c], hf, a0);                                    \
            a1 = MFMA16(whh[1][c], hf, a1);                                    \
        }                                                                      \
        u32x2 w0, w1;                                                          \
        w0[0] = pkbf(tanh_fast(a0[0]), tanh_fast(a0[1]));                      \
        w0[1] = pkbf(tanh_fast(a0[2]), tanh_fast(a0[3]));                      \
        w1[0] = pkbf(tanh_fast(a1[0]), tanh_fast(a1[1]));                      \
        w1[1] = pkbf(tanh_fast(a1[2]), tanh_fast(a1[3]));                      \
        *reinterpret_cast<u32x2*>(lds + ((P)^1)*4096 + hw[0]) = w0;            \
        *reinterpret_cast<u32x2*>(lds + ((P)^1)*4096 + hw[1]) = w1;            \
    }

__launch_bounds__(256, 1)
__global__ void rnn_fused_kernel(const float* __restrict__ x,
                                 const float* __restrict__ h0,
                                 const float* __restrict__ Wxh,
                                 const float* __restrict__ bxh,
                                 const float* __restrict__ Whh,
                                 const float* __restrict__ Wout,
                                 const float* __restrict__ bout,
                                 float* __restrict__ out)
{
    __shared__ __align__(16) char lds[2 * 4096];

    const int tid  = threadIdx.x;
    const int wv   = tid >> 6;
    const int lane = tid & 63;
    const int lg   = lane >> 4;
    const int lm   = lane & 15;
    const int b0   = blockIdx.x * BD;

    short8 wxh[2][4], whh[2][4];
    {
        const int col = 32*wv + lm;
        #pragma unroll
        for (int T = 0; T < 2; ++T) {
            #pragma unroll
            for (int c = 0; c < 4; ++c) {
                F8 fx, fh;
                #pragma unroll
                for (int e2 = 0; e2 < 4; ++e2) {
                    int k = 32*c + 8*lg + 2*e2;
                    fx.u[e2] = pkbf(Wxh[(size_t)k*HID + col + 16*T],
                                    Wxh[(size_t)(k+1)*HID + col + 16*T]);
                    fh.u[e2] = pkbf(Whh[(size_t)k*HID + col + 16*T],
                                    Whh[(size_t)(k+1)*HID + col + 16*T]);
                }
                wxh[T][c] = fx.s; whh[T][c] = fh.s;
            }
        }
    }
    float bx[2][4];
    #pragma unroll
    for (int T = 0; T < 2; ++T)
        #pragma unroll
        for (int r = 0; r < 4; ++r)
            bx[T][r] = bxh[32*wv + 16*T + 4*lg + r];

    int rd[4];
    #pragma unroll
    for (int c = 0; c < 4; ++c)
        rd[c] = (lm*256 + 64*c + 16*lg) ^ ((lm & 7) << 4);
    int hw[2];
    #pragma unroll
    for (int T = 0; T < 2; ++T)
        hw[T] = (lm*256 + 2*(32*wv + 16*T + 4*lg)) ^ ((lm & 7) << 4);

    {
        int b  = tid >> 4;
        int j0 = (tid & 15) * 8;
        const float* hp = h0 + (size_t)(b0 + b) * HID + j0;
        f4 v0 = *(const f4*)(hp);
        f4 v1 = *(const f4*)(hp + 4);
        F8 f;
        f.u[0] = pkbf(v0[0], v0[1]); f.u[1] = pkbf(v0[2], v0[3]);
        f.u[2] = pkbf(v1[0], v1[1]); f.u[3] = pkbf(v1[2], v1[3]);
        int off = (b*256 + 2*j0) ^ ((b & 7) << 4);
        *reinterpret_cast<short8*>(lds + off) = f.s;
    }

    const float* xq = x + (size_t)(b0 + lm) * SEQ * HID + 8*lg;
    f4 sA[8], sB[8];
    #pragma unroll
    for (int c = 0; c < 4; ++c) {
        sA[2*c]   = *(const f4*)(xq + 32*c);
        sA[2*c+1] = *(const f4*)(xq + 32*c + 4);
        sB[2*c]   = *(const f4*)(xq + HID + 32*c);
        sB[2*c+1] = *(const f4*)(xq + HID + 32*c + 4);
    }

    for (int t = 0; t < SEQ; t += 2) {
        RNN_STEP(sA, 0, 2, t);
        RNN_STEP(sB, 1, 3, t + 1);
        xq += 2 * HID;
    }

    block_sync();
    {
        short8 wo[2][4];
        const int col = 32*wv + lm;
        #pragma unroll
        for (int T = 0; T < 2; ++T) {
            #pragma unroll
            for (int c = 0; c < 4; ++c) {
                F8 f;
                #pragma unroll
                for (int e2 = 0; e2 < 4; ++e2) {
                    int k = 32*c + 8*lg + 2*e2;
                    f.u[e2] = pkbf(Wout[(size_t)k*HID + col + 16*T],
                                   Wout[(size_t)(k+1)*HID + col + 16*T]);
                }
                wo[T][c] = f.s;
            }
        }
        f32x4 o0 = {bout[32*wv + 4*lg + 0], bout[32*wv + 4*lg + 1],
                    bout[32*wv + 4*lg + 2], bout[32*wv + 4*lg + 3]};
        f32x4 o1 = {bout[32*wv + 16 + 4*lg + 0], bout[32*wv + 16 + 4*lg + 1],
                    bout[32*wv + 16 + 4*lg + 2], bout[32*wv + 16 + 4*lg + 3]};
        #pragma unroll
        for (int c = 0; c < 4; ++c) {
            short8 hf = *reinterpret_cast<const short8*>(lds + rd[c]);
            o0 = MFMA16(wo[0][c], hf, o0);
            o1 = MFMA16(wo[1][c], hf, o1);
        }
        float* op = out + (size_t)(b0 + lm) * HID + 32*wv + 4*lg;
        *reinterpret_cast<f4*>(op)      = o0;
        *reinterpret_cast<f4*>(op + 16) = o1;
    }
}

extern "C" void kernel_launch(void* const* d_in, const int* in_sizes, int n_in,
                              void* d_out, int out_size, void* d_ws, size_t ws_size,
                              hipStream_t stream) {
    const float* x    = (const float*)d_in[0];
    const float* h0   = (const float*)d_in[1];
    const float* Wxh  = (const float*)d_in[2];
    const float* bxh  = (const float*)d_in[3];
    const float* Whh  = (const float*)d_in[4];
    const float* Wout = (const float*)d_in[5];
    const float* bout = (const float*)d_in[6];
    (void)in_sizes; (void)n_in; (void)out_size;

    const size_t need = (size_t)BATCH * SEQ * HID * 2;  // 134 MB bf16 xh
    if (ws_size >= need) {
        __hip_bfloat16* xh = (__hip_bfloat16*)d_ws;
        xh_gemm_kernel<<<dim3(512), dim3(256), 0, stream>>>(x, Wxh, bxh, xh);
        rnn_rec16w_kernel<<<dim3(BATCH / 32), dim3(1024), 0, stream>>>(
            xh, h0, Whh, Wout, bout, (float*)d_out);
    } else {
        rnn_fused_kernel<<<dim3(BATCH / BD), dim3(256), 0, stream>>>(
            x, h0, Wxh, bxh, Whh, Wout, bout, (float*)d_out);
    }
}

// Round 10
// 922.347 us; speedup vs baseline: 1.3117x; 1.3117x over previous
//
#include <hip/hip_runtime.h>
#include <hip/hip_bf16.h>

// UnrolledRNN on MI355X (gfx950) — two-phase; 8-wave split-u recurrence (R8)
// + self-half-from-registers exchange trim (R10).
// Phase 1 (parallel, all CUs): xh[b,t,:] = x[b,t,:] @ Wxh + bxh -> bf16 in d_ws.
// Phase 2 (serial, 16 blocks x 8 waves): h = tanh(xh_t + h @ Whh).
//   Cost model (R8/R9 measured): per-CU LDS pipe drain of the 8-wave h
//   broadcast (32KB/step) + barrier + MFMA/tanh tail ~= 1025 cyc/step.
//   R10 trims bytes: each wave re-used its OWN 8B of frag jw from registers
//   (self2) and reads only the partner's 8B half via ds_read_b64; the 3
//   foreign frags stay b128. The u=1 wave's half-swapped B-frag layout is
//   compensated by loading its Whh A-frag with the SAME e-position
//   permutation (consistent A/B permutation cancels in the MFMA dot).
//   sigma mapping (R3-validated): wave (jw,u) owns j = 32jw + 8lg + 4u + r;
//   packed tanh output IS the half B-frag. 2-zone parity + 1 barrier/step.

#define SEQ   2048
#define HID   128
#define BATCH 256
#define BD    16

typedef __attribute__((ext_vector_type(8))) short    short8;
typedef __attribute__((ext_vector_type(4))) float    f32x4;
typedef __attribute__((ext_vector_type(4))) float    f4;
typedef __attribute__((ext_vector_type(2))) unsigned u32x2;
typedef __attribute__((ext_vector_type(4))) unsigned u32x4;

union F8 { unsigned u[4]; short8 s; };

__device__ __forceinline__ unsigned pkbf(float a, float b) {
    union { __hip_bfloat16 h[2]; unsigned u; } t;
    t.h[0] = __float2bfloat16(a);
    t.h[1] = __float2bfloat16(b);
    return t.u;
}

__device__ __forceinline__ float blo(unsigned u) {
    union { unsigned v; float f; } t; t.v = u << 16; return t.f;
}
__device__ __forceinline__ float bhi(unsigned u) {
    union { unsigned v; float f; } t; t.v = u & 0xffff0000u; return t.f;
}

__device__ __forceinline__ float tanh_fast(float x) {
    float e = __builtin_amdgcn_exp2f(x * 2.8853900817779268f);
    return 1.0f - 2.0f * __builtin_amdgcn_rcpf(e + 1.0f);
}

__device__ __forceinline__ void block_sync() {
    asm volatile("s_waitcnt lgkmcnt(0)" ::: "memory");
    __builtin_amdgcn_s_barrier();
    asm volatile("" ::: "memory");
}

#define MFMA16(A,B,C) __builtin_amdgcn_mfma_f32_16x16x32_bf16((A),(B),(C),0,0,0)

// =====================================================================
// Phase 1: xh = x @ Wxh + bxh, bf16 [BATCH*SEQ][HID] in ws (plain j order).
// =====================================================================
__launch_bounds__(256, 1)
__global__ void xh_gemm_kernel(const float* __restrict__ x,
                               const float* __restrict__ Wxh,
                               const float* __restrict__ bxh,
                               __hip_bfloat16* __restrict__ xh)
{
    const int tid  = threadIdx.x;
    const int wv   = tid >> 6;
    const int lane = tid & 63;
    const int lg   = lane >> 4;
    const int lm   = lane & 15;

    const int gw = blockIdx.x * 4 + wv;
    const int NW = gridDim.x * 4;
    const int NT = (BATCH * SEQ) / 16;

    short8 wa[8][4];
    {
        #pragma unroll
        for (int T = 0; T < 8; ++T) {
            #pragma unroll
            for (int c = 0; c < 4; ++c) {
                F8 f;
                #pragma unroll
                for (int e2 = 0; e2 < 4; ++e2) {
                    int k = 32*c + 8*lg + 2*e2;
                    f.u[e2] = pkbf(Wxh[(size_t)k*HID + 16*T + lm],
                                   Wxh[(size_t)(k+1)*HID + 16*T + lm]);
                }
                wa[T][c] = f.s;
            }
        }
    }
    float bb[8][4];
    #pragma unroll
    for (int T = 0; T < 8; ++T)
        #pragma unroll
        for (int r = 0; r < 4; ++r)
            bb[T][r] = bxh[16*T + 4*lg + r];

    for (int tile = gw; tile < NT; tile += NW) {
        const float* xp = x + (size_t)tile*16*HID + (size_t)lm*HID + 8*lg;
        f4 s[8];
        #pragma unroll
        for (int c = 0; c < 4; ++c) {
            s[2*c]   = *(const f4*)(xp + 32*c);
            s[2*c+1] = *(const f4*)(xp + 32*c + 4);
        }
        F8 xf[4];
        #pragma unroll
        for (int c = 0; c < 4; ++c) {
            xf[c].u[0] = pkbf(s[2*c][0],   s[2*c][1]);
            xf[c].u[1] = pkbf(s[2*c][2],   s[2*c][3]);
            xf[c].u[2] = pkbf(s[2*c+1][0], s[2*c+1][1]);
            xf[c].u[3] = pkbf(s[2*c+1][2], s[2*c+1][3]);
        }
        __hip_bfloat16* op = xh + (size_t)(tile*16 + lm) * HID;
        #pragma unroll
        for (int T = 0; T < 8; ++T) {
            f32x4 acc = {bb[T][0], bb[T][1], bb[T][2], bb[T][3]};
            #pragma unroll
            for (int c = 0; c < 4; ++c)
                acc = MFMA16(wa[T][c], xf[c].s, acc);
            u32x2 w;
            w[0] = pkbf(acc[0], acc[1]);
            w[1] = pkbf(acc[2], acc[3]);
            *reinterpret_cast<u32x2*>(op + 16*T + 4*lg) = w;
        }
    }
}

// =====================================================================
// Phase 2: 8-wave split-u recurrence, self-half from registers.
// LDS: zone[P in 0..1][c in 0..3][lane][16B] at P*4096 + c*1024 + lane*16.
// Wave (jw,u) writes its half-frag (8B) at zone^1 + jw*1024 + lane*16 + 8u.
// =====================================================================

#define REC8WB_STEP(S, P, POFF, TRT)                                          \
    {                                                                          \
        f32x4 a;                                                               \
        a[0] = blo(S[0]); a[1] = bhi(S[0]);                                    \
        a[2] = blo(S[1]); a[3] = bhi(S[1]);                                    \
        if ((TRT) + 4 < SEQ) S = *(const u32x2*)(xq + (POFF)*256);             \
        block_sync(); /* h_t frags complete in zone[P] */                      \
        const char* rb = lds + (P)*4096;                                       \
        short8 fA = *(const short8*)(rb + rdA);                                \
        short8 fB = *(const short8*)(rb + rdB);                                \
        short8 fC = *(const short8*)(rb + rdC);                                \
        u32x2  pp = *(const u32x2*)(rb + rdP);                                 \
        f32x4 tacc = {0.f, 0.f, 0.f, 0.f};                                     \
        a    = MFMA16(whfF[0], fA, a);                                         \
        tacc = MFMA16(whfF[1], fB, tacc);                                      \
        a    = MFMA16(whfF[2], fC, a);                                         \
        F8 sf;                                                                 \
        sf.u[0] = self2[0]; sf.u[1] = self2[1];                                \
        sf.u[2] = pp[0];    sf.u[3] = pp[1];                                   \
        tacc = MFMA16(whfS, sf.s, tacc);                                       \
        a += tacc;                                                             \
        u32x2 nf;                                                              \
        nf[0] = pkbf(tanh_fast(a[0]), tanh_fast(a[1]));                        \
        nf[1] = pkbf(tanh_fast(a[2]), tanh_fast(a[3]));                        \
        self2 = nf;                                                            \
        *reinterpret_cast<u32x2*>(lds + ((P)^1)*4096 + wr) = nf;               \
    }

__launch_bounds__(512, 1)
__global__ void rnn_rec8wb_kernel(const __hip_bfloat16* __restrict__ xh,
                                  const float* __restrict__ h0,
                                  const float* __restrict__ Whh,
                                  const float* __restrict__ Wout,
                                  const float* __restrict__ bout,
                                  float* __restrict__ out)
{
    __shared__ __align__(16) char lds[2 * 4096];  // 2 zones x 4 frags x 64 x 16B

    const int tid  = threadIdx.x;
    const int wv   = tid >> 6;        // 0..7
    const int jw   = wv & 3;          // j-slice
    const int u    = wv >> 2;         // half within slice
    const int lane = tid & 63;
    const int lg   = lane >> 4;
    const int lm   = lane & 15;
    const int b0   = blockIdx.x * BD;

    // sigma column (output j of acc slot): scol = 32jw + 8*(lm>>2) + 4u + (lm&3)
    const int scol = 32*jw + 8*(lm >> 2) + 4*u + (lm & 3);

    // Foreign-frag A operands (standard e-mapping): whfF[i] for c=(jw+1+i)&3,
    // pair e2: k = 32c + 8lg + 2e2.
    short8 whfF[3];
    #pragma unroll
    for (int i = 0; i < 3; ++i) {
        const int c = (jw + 1 + i) & 3;
        F8 f;
        #pragma unroll
        for (int e2 = 0; e2 < 4; ++e2) {
            int k = 32*c + 8*lg + 2*e2;
            f.u[e2] = pkbf(Whh[(size_t)k*HID + scol],
                           Whh[(size_t)(k+1)*HID + scol]);
        }
        whfF[i] = f.s;
    }
    // Self-frag A operand with e-position permutation matching the assembled
    // B-frag {own(4u..4u+3), partner(4(1-u)..)}: position 2e2 covers
    // k = 32jw + 8lg + ((2e2 + 4u) & 7).
    short8 whfS;
    {
        F8 f;
        #pragma unroll
        for (int e2 = 0; e2 < 4; ++e2) {
            int ko = (2*e2 + 4*u) & 7;
            int k  = 32*jw + 8*lg + ko;
            f.u[e2] = pkbf(Whh[(size_t)k*HID + scol],
                           Whh[(size_t)(k+1)*HID + scol]);
        }
        whfS = f.s;
    }

    // LDS offsets (zone-relative)
    const int rdA = ((jw + 1) & 3)*1024 + lane*16;
    const int rdB = ((jw + 2) & 3)*1024 + lane*16;
    const int rdC = ((jw + 3) & 3)*1024 + lane*16;
    const int rdP = jw*1024 + lane*16 + 8*(1 - u);   // partner half (b64)
    const int wr  = jw*1024 + lane*16 + 8*u;         // own half write

    // init zone0 + self2 from h0: own 4 values = h0[b0+lm][32jw+8lg+4u+{0..3}]
    u32x2 self2;
    {
        const float* hp = h0 + (size_t)(b0 + lm) * HID + 32*jw + 8*lg + 4*u;
        f4 v = *(const f4*)(hp);
        self2[0] = pkbf(v[0], v[1]);
        self2[1] = pkbf(v[2], v[3]);
        *reinterpret_cast<u32x2*>(lds + wr) = self2;
    }

    // xh stream: 8B/lane/step at xh[b0+lm][t][32jw+8lg+4u], 4-deep prefetch
    const char* xq = (const char*)xh + (size_t)(b0 + lm) * SEQ * 256
                   + (size_t)(32*jw + 8*lg + 4*u) * 2;

    u32x2 sA = *(const u32x2*)(xq + 0*256);
    u32x2 sB = *(const u32x2*)(xq + 1*256);
    u32x2 sC = *(const u32x2*)(xq + 2*256);
    u32x2 sD = *(const u32x2*)(xq + 3*256);

    for (int t = 0; t < SEQ; t += 4) {
        REC8WB_STEP(sA, 0, 4, t);
        REC8WB_STEP(sB, 1, 5, t + 1);
        REC8WB_STEP(sC, 0, 6, t + 2);
        REC8WB_STEP(sD, 1, 7, t + 3);
        xq += 4 * 256;
    }

    // epilogue: out = h_last @ Wout + bout; h_SEQ frags complete in zone0.
    // Wave wv computes output tile T = wv (j_out in [16T,16T+16)).
    block_sync();
    {
        const int T = wv;
        short8 h0f = *reinterpret_cast<const short8*>(lds + 0*1024 + lane*16);
        short8 h1f = *reinterpret_cast<const short8*>(lds + 1*1024 + lane*16);
        short8 h2f = *reinterpret_cast<const short8*>(lds + 2*1024 + lane*16);
        short8 h3f = *reinterpret_cast<const short8*>(lds + 3*1024 + lane*16);

        f32x4 o = {bout[16*T + 4*lg + 0], bout[16*T + 4*lg + 1],
                   bout[16*T + 4*lg + 2], bout[16*T + 4*lg + 3]};
        #pragma unroll
        for (int c = 0; c < 4; ++c) {
            F8 f;
            #pragma unroll
            for (int e2 = 0; e2 < 4; ++e2) {
                int k = 32*c + 8*lg + 2*e2;
                f.u[e2] = pkbf(Wout[(size_t)k*HID + 16*T + lm],
                               Wout[(size_t)(k+1)*HID + 16*T + lm]);
            }
            const short8 hf = (c == 0) ? h0f : (c == 1) ? h1f : (c == 2) ? h2f : h3f;
            o = MFMA16(f.s, hf, o);
        }
        float* op = out + (size_t)(b0 + lm) * HID + 16*T + 4*lg;
        *reinterpret_cast<f4*>(op) = o;
    }
}

// =====================================================================
// Fallback: verified round-1 monolithic kernel (used if ws too small).
// =====================================================================
#define RNN_STEP(SLOT, P, POFF, TRT)                                          \
    {                                                                          \
        F8 xf[4];                                                              \
        _Pragma("unroll")                                                      \
        for (int c = 0; c < 4; ++c) {                                          \
            xf[c].u[0] = pkbf(SLOT[2*c][0],   SLOT[2*c][1]);                   \
            xf[c].u[1] = pkbf(SLOT[2*c][2],   SLOT[2*c][3]);                   \
            xf[c].u[2] = pkbf(SLOT[2*c+1][0], SLOT[2*c+1][1]);                 \
            xf[c].u[3] = pkbf(SLOT[2*c+1][2], SLOT[2*c+1][3]);                 \
        }                                                                      \
        if ((TRT) + 2 < SEQ) {                                                 \
            _Pragma("unroll")                                                  \
            for (int c = 0; c < 4; ++c) {                                      \
                SLOT[2*c]   = *(const f4*)(xq + (POFF)*HID + 32*c);            \
                SLOT[2*c+1] = *(const f4*)(xq + (POFF)*HID + 32*c + 4);        \
            }                                                                  \
        }                                                                      \
        f32x4 a0 = {bx[0][0], bx[0][1], bx[0][2], bx[0][3]};                   \
        f32x4 a1 = {bx[1][0], bx[1][1], bx[1][2], bx[1][3]};                   \
        _Pragma("unroll")                                                      \
        for (int c = 0; c < 4; ++c) {                                          \
            a0 = MFMA16(wxh[0][c], xf[c].s, a0);                               \
            a1 = MFMA16(wxh[1][c], xf[c].s, a1);                               \
        }                                                                      \
        block_sync();                                                          \
        _Pragma("unroll")                                                      \
        for (int c = 0; c < 4; ++c) {                                          \
            short8 hf = *reinterpret_cast<const short8*>(lds + (P)*4096 + rd[c]); \
            a0 = MFMA16(whh[0][c], hf, a0);                                    \
            a1 = MFMA16(whh[1][c], hf, a1);                                    \
        }                                                                      \
        u32x2 w0, w1;                                                          \
        w0[0] = pkbf(tanh_fast(a0[0]), tanh_fast(a0[1]));                      \
        w0[1] = pkbf(tanh_fast(a0[2]), tanh_fast(a0[3]));                      \
        w1[0] = pkbf(tanh_fast(a1[0]), tanh_fast(a1[1]));                      \
        w1[1] = pkbf(tanh_fast(a1[2]), tanh_fast(a1[3]));                      \
        *reinterpret_cast<u32x2*>(lds + ((P)^1)*4096 + hw[0]) = w0;            \
        *reinterpret_cast<u32x2*>(lds + ((P)^1)*4096 + hw[1]) = w1;            \
    }

__launch_bounds__(256, 1)
__global__ void rnn_fused_kernel(const float* __restrict__ x,
                                 const float* __restrict__ h0,
                                 const float* __restrict__ Wxh,
                                 const float* __restrict__ bxh,
                                 const float* __restrict__ Whh,
                                 const float* __restrict__ Wout,
                                 const float* __restrict__ bout,
                                 float* __restrict__ out)
{
    __shared__ __align__(16) char lds[2 * 4096];

    const int tid  = threadIdx.x;
    const int wv   = tid >> 6;
    const int lane = tid & 63;
    const int lg   = lane >> 4;
    const int lm   = lane & 15;
    const int b0   = blockIdx.x * BD;

    short8 wxh[2][4], whh[2][4];
    {
        const int col = 32*wv + lm;
        #pragma unroll
        for (int T = 0; T < 2; ++T) {
            #pragma unroll
            for (int c = 0; c < 4; ++c) {
                F8 fx, fh;
                #pragma unroll
                for (int e2 = 0; e2 < 4; ++e2) {
                    int k = 32*c + 8*lg + 2*e2;
                    fx.u[e2] = pkbf(Wxh[(size_t)k*HID + col + 16*T],
                                    Wxh[(size_t)(k+1)*HID + col + 16*T]);
                    fh.u[e2] = pkbf(Whh[(size_t)k*HID + col + 16*T],
                                    Whh[(size_t)(k+1)*HID + col + 16*T]);
                }
                wxh[T][c] = fx.s; whh[T][c] = fh.s;
            }
        }
    }
    float bx[2][4];
    #pragma unroll
    for (int T = 0; T < 2; ++T)
        #pragma unroll
        for (int r = 0; r < 4; ++r)
            bx[T][r] = bxh[32*wv + 16*T + 4*lg + r];

    int rd[4];
    #pragma unroll
    for (int c = 0; c < 4; ++c)
        rd[c] = (lm*256 + 64*c + 16*lg) ^ ((lm & 7) << 4);
    int hw[2];
    #pragma unroll
    for (int T = 0; T < 2; ++T)
        hw[T] = (lm*256 + 2*(32*wv + 16*T + 4*lg)) ^ ((lm & 7) << 4);

    {
        int b  = tid >> 4;
        int j0 = (tid & 15) * 8;
        const float* hp = h0 + (size_t)(b0 + b) * HID + j0;
        f4 v0 = *(const f4*)(hp);
        f4 v1 = *(const f4*)(hp + 4);
        F8 f;
        f.u[0] = pkbf(v0[0], v0[1]); f.u[1] = pkbf(v0[2], v0[3]);
        f.u[2] = pkbf(v1[0], v1[1]); f.u[3] = pkbf(v1[2], v1[3]);
        int off = (b*256 + 2*j0) ^ ((b & 7) << 4);
        *reinterpret_cast<short8*>(lds + off) = f.s;
    }

    const float* xq = x + (size_t)(b0 + lm) * SEQ * HID + 8*lg;
    f4 sA[8], sB[8];
    #pragma unroll
    for (int c = 0; c < 4; ++c) {
        sA[2*c]   = *(const f4*)(xq + 32*c);
        sA[2*c+1] = *(const f4*)(xq + 32*c + 4);
        sB[2*c]   = *(const f4*)(xq + HID + 32*c);
        sB[2*c+1] = *(const f4*)(xq + HID + 32*c + 4);
    }

    for (int t = 0; t < SEQ; t += 2) {
        RNN_STEP(sA, 0, 2, t);
        RNN_STEP(sB, 1, 3, t + 1);
        xq += 2 * HID;
    }

    block_sync();
    {
        short8 wo[2][4];
        const int col = 32*wv + lm;
        #pragma unroll
        for (int T = 0; T < 2; ++T) {
            #pragma unroll
            for (int c = 0; c < 4; ++c) {
                F8 f;
                #pragma unroll
                for (int e2 = 0; e2 < 4; ++e2) {
                    int k = 32*c + 8*lg + 2*e2;
                    f.u[e2] = pkbf(Wout[(size_t)k*HID + col + 16*T],
                                   Wout[(size_t)(k+1)*HID + col + 16*T]);
                }
                wo[T][c] = f.s;
            }
        }
        f32x4 o0 = {bout[32*wv + 4*lg + 0], bout[32*wv + 4*lg + 1],
                    bout[32*wv + 4*lg + 2], bout[32*wv + 4*lg + 3]};
        f32x4 o1 = {bout[32*wv + 16 + 4*lg + 0], bout[32*wv + 16 + 4*lg + 1],
                    bout[32*wv + 16 + 4*lg + 2], bout[32*wv + 16 + 4*lg + 3]};
        #pragma unroll
        for (int c = 0; c < 4; ++c) {
            short8 hf = *reinterpret_cast<const short8*>(lds + rd[c]);
            o0 = MFMA16(wo[0][c], hf, o0);
            o1 = MFMA16(wo[1][c], hf, o1);
        }
        float* op = out + (size_t)(b0 + lm) * HID + 32*wv + 4*lg;
        *reinterpret_cast<f4*>(op)      = o0;
        *reinterpret_cast<f4*>(op + 16) = o1;
    }
}

extern "C" void kernel_launch(void* const* d_in, const int* in_sizes, int n_in,
                              void* d_out, int out_size, void* d_ws, size_t ws_size,
                              hipStream_t stream) {
    const float* x    = (const float*)d_in[0];
    const float* h0   = (const float*)d_in[1];
    const float* Wxh  = (const float*)d_in[2];
    const float* bxh  = (const float*)d_in[3];
    const float* Whh  = (const float*)d_in[4];
    const float* Wout = (const float*)d_in[5];
    const float* bout = (const float*)d_in[6];
    (void)in_sizes; (void)n_in; (void)out_size;

    const size_t need = (size_t)BATCH * SEQ * HID * 2;  // 134 MB bf16 xh
    if (ws_size >= need) {
        __hip_bfloat16* xh = (__hip_bfloat16*)d_ws;
        xh_gemm_kernel<<<dim3(512), dim3(256), 0, stream>>>(x, Wxh, bxh, xh);
        rnn_rec8wb_kernel<<<dim3(BATCH / BD), dim3(512), 0, stream>>>(
            xh, h0, Whh, Wout, bout, (float*)d_out);
    } else {
        rnn_fused_kernel<<<dim3(BATCH / BD), dim3(256), 0, stream>>>(
            x, h0, Wxh, bxh, Whh, Wout, bout, (float*)d_out);
    }
}

// Round 11
// 905.736 us; speedup vs baseline: 1.3357x; 1.0183x over previous
//
#include <hip/hip_runtime.h>
#include <hip/hip_bf16.h>

// UnrolledRNN on MI355X (gfx950) — two-phase; 8-wave split-u recurrence.
// REVERT to R8 (best measured: rec 876us, total 903us). R9 (16 waves, 8 CU),
// R10 (byte-trim) both regressed; R2-R10 probes establish the structural
// floor of the barrier-exchange recurrence at ~1000 cyc/step:
//   LDS h-broadcast pipe (8 waves x 4KB ~ 385cyc, algorithmically pinned)
//   + barrier (~150-200) + LDS write->read round-trip (~250) + MFMA/tanh
//   tail (~200), partially overlapped by 2 waves/SIMD.
// Phase 1 (parallel, all CUs): xh[b,t,:] = x[b,t,:] @ Wxh + bxh -> bf16 in d_ws.
// Phase 2 (serial, 16 blocks x 8 waves = 512 thr): h = tanh(xh_t + h @ Whh).
//   Wave (jw,u) (jw=wv&3, u=wv>>2) owns the u-half of j-slice jw:
//   acc reg r <-> j = 32jw + 8lg + 4u + r (R3-validated sigma, u fixed).
//   Per step/wave: 8B xh load, 4 ds_read_b128 (all frags), 4 MFMA (2+2 tree),
//   4 tanh, 1 ds_write_b64 (half-frag at lane*16+8u). Waves wv and wv+4 share
//   a SIMD -> each other's MFMA-block/LDS/trans latencies are hidden.
//   2-zone parity + 1 barrier/step.

#define SEQ   2048
#define HID   128
#define BATCH 256
#define BD    16

typedef __attribute__((ext_vector_type(8))) short    short8;
typedef __attribute__((ext_vector_type(4))) float    f32x4;
typedef __attribute__((ext_vector_type(4))) float    f4;
typedef __attribute__((ext_vector_type(2))) unsigned u32x2;
typedef __attribute__((ext_vector_type(4))) unsigned u32x4;

union F8 { unsigned u[4]; short8 s; };

__device__ __forceinline__ unsigned pkbf(float a, float b) {
    union { __hip_bfloat16 h[2]; unsigned u; } t;
    t.h[0] = __float2bfloat16(a);
    t.h[1] = __float2bfloat16(b);
    return t.u;
}

__device__ __forceinline__ float blo(unsigned u) {
    union { unsigned v; float f; } t; t.v = u << 16; return t.f;
}
__device__ __forceinline__ float bhi(unsigned u) {
    union { unsigned v; float f; } t; t.v = u & 0xffff0000u; return t.f;
}

__device__ __forceinline__ float tanh_fast(float x) {
    float e = __builtin_amdgcn_exp2f(x * 2.8853900817779268f);
    return 1.0f - 2.0f * __builtin_amdgcn_rcpf(e + 1.0f);
}

__device__ __forceinline__ void block_sync() {
    asm volatile("s_waitcnt lgkmcnt(0)" ::: "memory");
    __builtin_amdgcn_s_barrier();
    asm volatile("" ::: "memory");
}

#define MFMA16(A,B,C) __builtin_amdgcn_mfma_f32_16x16x32_bf16((A),(B),(C),0,0,0)

// =====================================================================
// Phase 1: xh = x @ Wxh + bxh, bf16 [BATCH*SEQ][HID] in ws (plain j order).
// =====================================================================
__launch_bounds__(256, 1)
__global__ void xh_gemm_kernel(const float* __restrict__ x,
                               const float* __restrict__ Wxh,
                               const float* __restrict__ bxh,
                               __hip_bfloat16* __restrict__ xh)
{
    const int tid  = threadIdx.x;
    const int wv   = tid >> 6;
    const int lane = tid & 63;
    const int lg   = lane >> 4;
    const int lm   = lane & 15;

    const int gw = blockIdx.x * 4 + wv;
    const int NW = gridDim.x * 4;
    const int NT = (BATCH * SEQ) / 16;

    short8 wa[8][4];
    {
        #pragma unroll
        for (int T = 0; T < 8; ++T) {
            #pragma unroll
            for (int c = 0; c < 4; ++c) {
                F8 f;
                #pragma unroll
                for (int e2 = 0; e2 < 4; ++e2) {
                    int k = 32*c + 8*lg + 2*e2;
                    f.u[e2] = pkbf(Wxh[(size_t)k*HID + 16*T + lm],
                                   Wxh[(size_t)(k+1)*HID + 16*T + lm]);
                }
                wa[T][c] = f.s;
            }
        }
    }
    float bb[8][4];
    #pragma unroll
    for (int T = 0; T < 8; ++T)
        #pragma unroll
        for (int r = 0; r < 4; ++r)
            bb[T][r] = bxh[16*T + 4*lg + r];

    for (int tile = gw; tile < NT; tile += NW) {
        const float* xp = x + (size_t)tile*16*HID + (size_t)lm*HID + 8*lg;
        f4 s[8];
        #pragma unroll
        for (int c = 0; c < 4; ++c) {
            s[2*c]   = *(const f4*)(xp + 32*c);
            s[2*c+1] = *(const f4*)(xp + 32*c + 4);
        }
        F8 xf[4];
        #pragma unroll
        for (int c = 0; c < 4; ++c) {
            xf[c].u[0] = pkbf(s[2*c][0],   s[2*c][1]);
            xf[c].u[1] = pkbf(s[2*c][2],   s[2*c][3]);
            xf[c].u[2] = pkbf(s[2*c+1][0], s[2*c+1][1]);
            xf[c].u[3] = pkbf(s[2*c+1][2], s[2*c+1][3]);
        }
        __hip_bfloat16* op = xh + (size_t)(tile*16 + lm) * HID;
        #pragma unroll
        for (int T = 0; T < 8; ++T) {
            f32x4 acc = {bb[T][0], bb[T][1], bb[T][2], bb[T][3]};
            #pragma unroll
            for (int c = 0; c < 4; ++c)
                acc = MFMA16(wa[T][c], xf[c].s, acc);
            u32x2 w;
            w[0] = pkbf(acc[0], acc[1]);
            w[1] = pkbf(acc[2], acc[3]);
            *reinterpret_cast<u32x2*>(op + 16*T + 4*lg) = w;
        }
    }
}

// =====================================================================
// Phase 2: 8-wave split-u recurrence.
// LDS: zone[P in 0..1][c in 0..3][lane][16B] at P*4096 + c*1024 + lane*16.
// Wave (jw,u) writes its half-frag (8B) at zone^1 + jw*1024 + lane*16 + 8u.
// =====================================================================

#define REC8W_STEP(S, P, POFF, TRT)                                           \
    {                                                                          \
        f32x4 a;                                                               \
        a[0] = blo(S[0]); a[1] = bhi(S[0]);                                    \
        a[2] = blo(S[1]); a[3] = bhi(S[1]);                                    \
        if ((TRT) + 4 < SEQ) S = *(const u32x2*)(xq + (POFF)*256);             \
        block_sync(); /* h_t frags complete in zone[P] */                      \
        const char* rb = lds + (P)*4096;                                       \
        short8 f0 = *(const short8*)(rb + 0*1024 + lane*16);                   \
        short8 f1 = *(const short8*)(rb + 1*1024 + lane*16);                   \
        short8 f2 = *(const short8*)(rb + 2*1024 + lane*16);                   \
        short8 f3 = *(const short8*)(rb + 3*1024 + lane*16);                   \
        f32x4 tacc = {0.f, 0.f, 0.f, 0.f};                                     \
        a    = MFMA16(whf[0], f0, a);                                          \
        tacc = MFMA16(whf[2], f2, tacc);                                       \
        a    = MFMA16(whf[1], f1, a);                                          \
        tacc = MFMA16(whf[3], f3, tacc);                                       \
        a += tacc;                                                             \
        u32x2 nf;                                                              \
        nf[0] = pkbf(tanh_fast(a[0]), tanh_fast(a[1]));                        \
        nf[1] = pkbf(tanh_fast(a[2]), tanh_fast(a[3]));                        \
        *reinterpret_cast<u32x2*>(lds + ((P)^1)*4096 + wr) = nf;               \
    }

__launch_bounds__(512, 1)
__global__ void rnn_rec8w_kernel(const __hip_bfloat16* __restrict__ xh,
                                 const float* __restrict__ h0,
                                 const float* __restrict__ Whh,
                                 const float* __restrict__ Wout,
                                 const float* __restrict__ bout,
                                 float* __restrict__ out)
{
    __shared__ __align__(16) char lds[2 * 4096];  // 2 zones x 4 frags x 64 x 16B

    const int tid  = threadIdx.x;
    const int wv   = tid >> 6;        // 0..7
    const int jw   = wv & 3;          // j-slice
    const int u    = wv >> 2;         // half within slice
    const int lane = tid & 63;
    const int lg   = lane >> 4;
    const int lm   = lane & 15;
    const int b0   = blockIdx.x * BD;

    // Whh A-frags (R3-validated sigma, u fixed per wave):
    // whf[c] lane (lg,lm) elem-pair e2 = Whh[32c+8lg+2e2 (+1)][scol],
    // scol = 32jw + 8*(lm>>2) + 4u + (lm&3).
    short8 whf[4];
    {
        const int scol = 32*jw + 8*(lm >> 2) + 4*u + (lm & 3);
        #pragma unroll
        for (int c = 0; c < 4; ++c) {
            F8 f;
            #pragma unroll
            for (int e2 = 0; e2 < 4; ++e2) {
                int k = 32*c + 8*lg + 2*e2;
                f.u[e2] = pkbf(Whh[(size_t)k*HID + scol],
                               Whh[(size_t)(k+1)*HID + scol]);
            }
            whf[c] = f.s;
        }
    }

    // LDS write offset for this wave's half-frag
    const int wr = jw*1024 + lane*16 + 8*u;

    // init zone0 from h0: this wave's 4 values = h0[b0+lm][32jw+8lg+4u+{0..3}]
    {
        const float* hp = h0 + (size_t)(b0 + lm) * HID + 32*jw + 8*lg + 4*u;
        f4 v = *(const f4*)(hp);
        u32x2 iv;
        iv[0] = pkbf(v[0], v[1]);
        iv[1] = pkbf(v[2], v[3]);
        *reinterpret_cast<u32x2*>(lds + wr) = iv;
    }

    // xh stream: 8B/lane/step at xh[b0+lm][t][32jw+8lg+4u], 4-deep prefetch
    const char* xq = (const char*)xh + (size_t)(b0 + lm) * SEQ * 256
                   + (size_t)(32*jw + 8*lg + 4*u) * 2;

    u32x2 sA = *(const u32x2*)(xq + 0*256);
    u32x2 sB = *(const u32x2*)(xq + 1*256);
    u32x2 sC = *(const u32x2*)(xq + 2*256);
    u32x2 sD = *(const u32x2*)(xq + 3*256);

    for (int t = 0; t < SEQ; t += 4) {
        REC8W_STEP(sA, 0, 4, t);
        REC8W_STEP(sB, 1, 5, t + 1);
        REC8W_STEP(sC, 0, 6, t + 2);
        REC8W_STEP(sD, 1, 7, t + 3);
        xq += 4 * 256;
    }

    // epilogue: out = h_last @ Wout + bout; h_SEQ frags in zone0.
    // Wave wv computes output tile T = wv (j_out in [16T,16T+16)).
    block_sync();
    {
        const int T = wv;
        short8 h0f = *reinterpret_cast<const short8*>(lds + 0*1024 + lane*16);
        short8 h1f = *reinterpret_cast<const short8*>(lds + 1*1024 + lane*16);
        short8 h2f = *reinterpret_cast<const short8*>(lds + 2*1024 + lane*16);
        short8 h3f = *reinterpret_cast<const short8*>(lds + 3*1024 + lane*16);

        f32x4 o = {bout[16*T + 4*lg + 0], bout[16*T + 4*lg + 1],
                   bout[16*T + 4*lg + 2], bout[16*T + 4*lg + 3]};
        #pragma unroll
        for (int c = 0; c < 4; ++c) {
            F8 f;
            #pragma unroll
            for (int e2 = 0; e2 < 4; ++e2) {
                int k = 32*c + 8*lg + 2*e2;
                f.u[e2] = pkbf(Wout[(size_t)k*HID + 16*T + lm],
                               Wout[(size_t)(k+1)*HID + 16*T + lm]);
            }
            const short8 hf = (c == 0) ? h0f : (c == 1) ? h1f : (c == 2) ? h2f : h3f;
            o = MFMA16(f.s, hf, o);
        }
        float* op = out + (size_t)(b0 + lm) * HID + 16*T + 4*lg;
        *reinterpret_cast<f4*>(op) = o;
    }
}

// =====================================================================
// Fallback: verified round-1 monolithic kernel (used if ws too small).
// =====================================================================
#define RNN_STEP(SLOT, P, POFF, TRT)                                          \
    {                                                                          \
        F8 xf[4];                                                              \
        _Pragma("unroll")                                                      \
        for (int c = 0; c < 4; ++c) {                                          \
            xf[c].u[0] = pkbf(SLOT[2*c][0],   SLOT[2*c][1]);                   \
            xf[c].u[1] = pkbf(SLOT[2*c][2],   SLOT[2*c][3]);                   \
            xf[c].u[2] = pkbf(SLOT[2*c+1][0], SLOT[2*c+1][1]);                 \
            xf[c].u[3] = pkbf(SLOT[2*c+1][2], SLOT[2*c+1][3]);                 \
        }                                                                      \
        if ((TRT) + 2 < SEQ) {                                                 \
            _Pragma("unroll")                                                  \
            for (int c = 0; c < 4; ++c) {                                      \
                SLOT[2*c]   = *(const f4*)(xq + (POFF)*HID + 32*c);            \
                SLOT[2*c+1] = *(const f4*)(xq + (POFF)*HID + 32*c + 4);        \
            }                                                                  \
        }                                                                      \
        f32x4 a0 = {bx[0][0], bx[0][1], bx[0][2], bx[0][3]};                   \
        f32x4 a1 = {bx[1][0], bx[1][1], bx[1][2], bx[1][3]};                   \
        _Pragma("unroll")                                                      \
        for (int c = 0; c < 4; ++c) {                                          \
            a0 = MFMA16(wxh[0][c], xf[c].s, a0);                               \
            a1 = MFMA16(wxh[1][c], xf[c].s, a1);                               \
        }                                                                      \
        block_sync();                                                          \
        _Pragma("unroll")                                                      \
        for (int c = 0; c < 4; ++c) {                                          \
            short8 hf = *reinterpret_cast<const short8*>(lds + (P)*4096 + rd[c]); \
            a0 = MFMA16(whh[0][c], hf, a0);                                    \
            a1 = MFMA16(whh[1][c], hf, a1);                                    \
        }                                                                      \
        u32x2 w0, w1;                                                          \
        w0[0] = pkbf(tanh_fast(a0[0]), tanh_fast(a0[1]));                      \
        w0[1] = pkbf(tanh_fast(a0[2]), tanh_fast(a0[3]));                      \
        w1[0] = pkbf(tanh_fast(a1[0]), tanh_fast(a1[1]));                      \
        w1[1] = pkbf(tanh_fast(a1[2]), tanh_fast(a1[3]));                      \
        *reinterpret_cast<u32x2*>(lds + ((P)^1)*4096 + hw[0]) = w0;            \
        *reinterpret_cast<u32x2*>(lds + ((P)^1)*4096 + hw[1]) = w1;            \
    }

__launch_bounds__(256, 1)
__global__ void rnn_fused_kernel(const float* __restrict__ x,
                                 const float* __restrict__ h0,
                                 const float* __restrict__ Wxh,
                                 const float* __restrict__ bxh,
                                 const float* __restrict__ Whh,
                                 const float* __restrict__ Wout,
                                 const float* __restrict__ bout,
                                 float* __restrict__ out)
{
    __shared__ __align__(16) char lds[2 * 4096];

    const int tid  = threadIdx.x;
    const int wv   = tid >> 6;
    const int lane = tid & 63;
    const int lg   = lane >> 4;
    const int lm   = lane & 15;
    const int b0   = blockIdx.x * BD;

    short8 wxh[2][4], whh[2][4];
    {
        const int col = 32*wv + lm;
        #pragma unroll
        for (int T = 0; T < 2; ++T) {
            #pragma unroll
            for (int c = 0; c < 4; ++c) {
                F8 fx, fh;
                #pragma unroll
                for (int e2 = 0; e2 < 4; ++e2) {
                    int k = 32*c + 8*lg + 2*e2;
                    fx.u[e2] = pkbf(Wxh[(size_t)k*HID + col + 16*T],
                                    Wxh[(size_t)(k+1)*HID + col + 16*T]);
                    fh.u[e2] = pkbf(Whh[(size_t)k*HID + col + 16*T],
                                    Whh[(size_t)(k+1)*HID + col + 16*T]);
                }
                wxh[T][c] = fx.s; whh[T][c] = fh.s;
            }
        }
    }
    float bx[2][4];
    #pragma unroll
    for (int T = 0; T < 2; ++T)
        #pragma unroll
        for (int r = 0; r < 4; ++r)
            bx[T][r] = bxh[32*wv + 16*T + 4*lg + r];

    int rd[4];
    #pragma unroll
    for (int c = 0; c < 4; ++c)
        rd[c] = (lm*256 + 64*c + 16*lg) ^ ((lm & 7) << 4);
    int hw[2];
    #pragma unroll
    for (int T = 0; T < 2; ++T)
        hw[T] = (lm*256 + 2*(32*wv + 16*T + 4*lg)) ^ ((lm & 7) << 4);

    {
        int b  = tid >> 4;
        int j0 = (tid & 15) * 8;
        const float* hp = h0 + (size_t)(b0 + b) * HID + j0;
        f4 v0 = *(const f4*)(hp);
        f4 v1 = *(const f4*)(hp + 4);
        F8 f;
        f.u[0] = pkbf(v0[0], v0[1]); f.u[1] = pkbf(v0[2], v0[3]);
        f.u[2] = pkbf(v1[0], v1[1]); f.u[3] = pkbf(v1[2], v1[3]);
        int off = (b*256 + 2*j0) ^ ((b & 7) << 4);
        *reinterpret_cast<short8*>(lds + off) = f.s;
    }

    const float* xq = x + (size_t)(b0 + lm) * SEQ * HID + 8*lg;
    f4 sA[8], sB[8];
    #pragma unroll
    for (int c = 0; c < 4; ++c) {
        sA[2*c]   = *(const f4*)(xq + 32*c);
        sA[2*c+1] = *(const f4*)(xq + 32*c + 4);
        sB[2*c]   = *(const f4*)(xq + HID + 32*c);
        sB[2*c+1] = *(const f4*)(xq + HID + 32*c + 4);
    }

    for (int t = 0; t < SEQ; t += 2) {
        RNN_STEP(sA, 0, 2, t);
        RNN_STEP(sB, 1, 3, t + 1);
        xq += 2 * HID;
    }

    block_sync();
    {
        short8 wo[2][4];
        const int col = 32*wv + lm;
        #pragma unroll
        for (int T = 0; T < 2; ++T) {
            #pragma unroll
            for (int c = 0; c < 4; ++c) {
                F8 f;
                #pragma unroll
                for (int e2 = 0; e2 < 4; ++e2) {
                    int k = 32*c + 8*lg + 2*e2;
                    f.u[e2] = pkbf(Wout[(size_t)k*HID + col + 16*T],
                                   Wout[(size_t)(k+1)*HID + col + 16*T]);
                }
                wo[T][c] = f.s;
            }
        }
        f32x4 o0 = {bout[32*wv + 4*lg + 0], bout[32*wv + 4*lg + 1],
                    bout[32*wv + 4*lg + 2], bout[32*wv + 4*lg + 3]};
        f32x4 o1 = {bout[32*wv + 16 + 4*lg + 0], bout[32*wv + 16 + 4*lg + 1],
                    bout[32*wv + 16 + 4*lg + 2], bout[32*wv + 16 + 4*lg + 3]};
        #pragma unroll
        for (int c = 0; c < 4; ++c) {
            short8 hf = *reinterpret_cast<const short8*>(lds + rd[c]);
            o0 = MFMA16(wo[0][c], hf, o0);
            o1 = MFMA16(wo[1][c], hf, o1);
        }
        float* op = out + (size_t)(b0 + lm) * HID + 32*wv + 4*lg;
        *reinterpret_cast<f4*>(op)      = o0;
        *reinterpret_cast<f4*>(op + 16) = o1;
    }
}

extern "C" void kernel_launch(void* const* d_in, const int* in_sizes, int n_in,
                              void* d_out, int out_size, void* d_ws, size_t ws_size,
                              hipStream_t stream) {
    const float* x    = (const float*)d_in[0];
    const float* h0   = (const float*)d_in[1];
    const float* Wxh  = (const float*)d_in[2];
    const float* bxh  = (const float*)d_in[3];
    const float* Whh  = (const float*)d_in[4];
    const float* Wout = (const float*)d_in[5];
    const float* bout = (const float*)d_in[6];
    (void)in_sizes; (void)n_in; (void)out_size;

    const size_t need = (size_t)BATCH * SEQ * HID * 2;  // 134 MB bf16 xh
    if (ws_size >= need) {
        __hip_bfloat16* xh = (__hip_bfloat16*)d_ws;
        xh_gemm_kernel<<<dim3(512), dim3(256), 0, stream>>>(x, Wxh, bxh, xh);
        rnn_rec8w_kernel<<<dim3(BATCH / BD), dim3(512), 0, stream>>>(
            xh, h0, Whh, Wout, bout, (float*)d_out);
    } else {
        rnn_fused_kernel<<<dim3(BATCH / BD), dim3(256), 0, stream>>>(
            x, h0, Wxh, bxh, Whh, Wout, bout, (float*)d_out);
    }
}